// Round 4
// baseline (107.679 us; speedup 1.0000x reference)
//
#include <hip/hip_runtime.h>
#include <hip/hip_bf16.h>

typedef __attribute__((ext_vector_type(8))) short bf16x8;
typedef __attribute__((ext_vector_type(4))) float f32x4;

#define KDIM 2048
#define BK 64
#define NKT (KDIM / BK)

__device__ __forceinline__ unsigned short f2bf(float f) {
  union { float fv; unsigned int u; } c; c.fv = f;
  unsigned int u = c.u;
  unsigned int r = (u + 0x7FFFu + ((u >> 16) & 1u)) >> 16;
  return (unsigned short)r;
}

__device__ __forceinline__ void gload_lds16(const unsigned short* g, unsigned short* l) {
  auto gp = reinterpret_cast<const __attribute__((address_space(1))) unsigned int*>(
      reinterpret_cast<uintptr_t>(g));
  auto lp = reinterpret_cast<__attribute__((address_space(3))) unsigned int*>(
      reinterpret_cast<uintptr_t>(l));
  __builtin_amdgcn_global_load_lds(gp, lp, 16, 0, 0);
}

__device__ __forceinline__ float sigm(float z) { return 1.0f / (1.0f + __expf(-z)); }
__device__ __forceinline__ float tanh_fast(float z) { return 1.0f - 2.0f / (__expf(2.0f * z) + 1.0f); }

template <int CTRL>
__device__ __forceinline__ float dppf(float v) {
  return __int_as_float(__builtin_amdgcn_mov_dpp(__float_as_int(v), CTRL, 0xF, 0xF, true));
}

// Build hx = [x | h] as bf16 [4096][2048]
__global__ void pack_hx_kernel(const float* __restrict__ x, const float* __restrict__ h,
                               unsigned short* __restrict__ hx) {
  int idx = (blockIdx.x * blockDim.x + threadIdx.x) * 4;
  int row = idx >> 11;
  int col = idx & 2047;
  const float* src = (col < 1024) ? (x + (size_t)row * 1024 + col)
                                  : (h + (size_t)row * 1024 + (col - 1024));
  float4 v = *reinterpret_cast<const float4*>(src);
  ushort4 o = make_ushort4(f2bf(v.x), f2bf(v.y), f2bf(v.z), f2bf(v.w));
  *reinterpret_cast<ushort4*>(hx + idx) = o;
}

// W[g] [2048][1024] f32 -> wt2 bf16, interleaved rows: R = col*4 + gate, [4096][2048]
__global__ void transpose_w4_kernel(const float* __restrict__ W0, const float* __restrict__ W1,
                                    const float* __restrict__ W2, const float* __restrict__ W3,
                                    unsigned short* __restrict__ wt2) {
  __shared__ float tile[32][33];
  const int g = blockIdx.z;
  const float* W = (g == 0) ? W0 : (g == 1) ? W1 : (g == 2) ? W2 : W3;
  int n0 = blockIdx.x * 32;
  int k0 = blockIdx.y * 32;
  int tx = threadIdx.x;
  int ty = threadIdx.y;
#pragma unroll
  for (int i = 0; i < 4; ++i)
    tile[ty + 8 * i][tx] = W[(size_t)(k0 + ty + 8 * i) * 1024 + (n0 + tx)];
  __syncthreads();
#pragma unroll
  for (int i = 0; i < 4; ++i)
    wt2[((size_t)(n0 + ty + 8 * i) * 4 + g) * 2048 + (k0 + tx)] = f2bf(tile[tx][ty + 8 * i]);
}

#define LGKM0 asm volatile("s_waitcnt lgkmcnt(0)" ::: "memory"); __builtin_amdgcn_sched_barrier(0);
#define VMCNT(N) asm volatile("s_waitcnt vmcnt(" #N ")" ::: "memory"); __builtin_amdgcn_sched_barrier(0);

#define RD_A(DST, BASE, MB)                                                          \
  _Pragma("unroll") for (int m = 0; m < 4; ++m) {                                    \
    DST[m][0] = *reinterpret_cast<const bf16x8*>((BASE) + aoff0 + ((MB) + m) * 1024);\
    DST[m][1] = *reinterpret_cast<const bf16x8*>((BASE) + aoff1 + ((MB) + m) * 1024);\
  }

#define RD_B(DST, BASE, NB)                                                          \
  _Pragma("unroll") for (int n = 0; n < 2; ++n) {                                    \
    DST[n][0] = *reinterpret_cast<const bf16x8*>((BASE) + boff0 + ((NB) + n) * 1024);\
    DST[n][1] = *reinterpret_cast<const bf16x8*>((BASE) + boff1 + ((NB) + n) * 1024);\
  }

#define QUAD(MH, NH, AFR, BFR)                                                       \
  _Pragma("unroll") for (int m = 0; m < 4; ++m)                                      \
  _Pragma("unroll") for (int n = 0; n < 2; ++n) {                                    \
    acc[(MH)*4+m][(NH)*2+n] = __builtin_amdgcn_mfma_f32_16x16x32_bf16(               \
        AFR[m][0], BFR[n][0], acc[(MH)*4+m][(NH)*2+n], 0, 0, 0);                     \
    acc[(MH)*4+m][(NH)*2+n] = __builtin_amdgcn_mfma_f32_16x16x32_bf16(               \
        AFR[m][1], BFR[n][1], acc[(MH)*4+m][(NH)*2+n], 0, 0, 0);                     \
  }

// Fused 4-gate GEMM (m201 256^2 8-phase geometry, gate-interleaved N) + dpp epilogue.
// Grid: 256 blocks, 512 threads (8 waves: 2M x 4N, wave out 128 rows x 64 logical cols).
__global__ __launch_bounds__(512, 2) void lstm_fused_kernel(
    const unsigned short* __restrict__ hx,
    const unsigned short* __restrict__ wt2,
    const float* __restrict__ bias_f,
    const float* __restrict__ bias_i,
    const float* __restrict__ bias_s,
    const float* __restrict__ bias_p,
    const float* __restrict__ c_in,
    float* __restrict__ out) {
  __shared__ unsigned short lA[2][256 * BK];  // 2 x 32 KB
  __shared__ unsigned short lB[2][256 * BK];  // 2 x 32 KB

  const int tid  = threadIdx.x;
  const int lane = tid & 63;
  const int wid  = tid >> 6;
  const int wr   = wid >> 2;  // 0..1 : 128-row slice
  const int wc   = wid & 3;   // 0..3 : 64-logical-col slice
  const int lg   = lane >> 4;
  const int ll   = lane & 15;

  // bijective XCD swizzle (256 % 8 == 0)
  const int wg   = (blockIdx.x & 7) * 32 + (blockIdx.x >> 3);
  const int brow = wg >> 4;  // 0..15
  const int bcol = wg & 15;  // 0..15

  // ---- staging descriptors ----
  unsigned int dAB[4];
  const unsigned short* srcA[4];
  const unsigned short* srcB[4];
#pragma unroll
  for (int h = 0; h < 2; ++h)
#pragma unroll
    for (int j = 0; j < 2; ++j) {
      int i = h * 2 + j;
      int s = j * 512 + tid;
      int r = h * 128 + (s >> 3);
      int ch = (s & 7) ^ (r & 7);
      dAB[i] = h * 8192 + s * 8;
      srcA[i] = hx  + (size_t)(brow * 256 + r) * KDIM + ch * 8;
      srcB[i] = wt2 + (size_t)(bcol * 256 + r) * KDIM + ch * 8;
    }

  // ---- fragment LDS offsets (row&7 == ll&7 for all frags) ----
  const int ch0 = lg ^ (ll & 7);
  const int ch1 = (4 + lg) ^ (ll & 7);
  const unsigned aoff0 = (unsigned)((wr * 128 + ll) * 64 + ch0 * 8);
  const unsigned aoff1 = (unsigned)((wr * 128 + ll) * 64 + ch1 * 8);
  const unsigned boff0 = (unsigned)((wc * 64 + ll) * 64 + ch0 * 8);
  const unsigned boff1 = (unsigned)((wc * 64 + ll) * 64 + ch1 * 8);

  f32x4 acc[8][4];
#pragma unroll
  for (int m = 0; m < 8; ++m)
#pragma unroll
    for (int n = 0; n < 4; ++n)
      acc[m][n] = (f32x4)(0.0f);

  // ---- prologue: stage tiles 0 (buf0) and 1 (buf1) ----
#pragma unroll
  for (int i = 0; i < 4; ++i) gload_lds16(srcB[i], &lB[0][dAB[i]]);
#pragma unroll
  for (int i = 0; i < 4; ++i) gload_lds16(srcA[i], &lA[0][dAB[i]]);
#pragma unroll
  for (int i = 0; i < 4; ++i) { srcA[i] += BK; srcB[i] += BK; }
#pragma unroll
  for (int i = 0; i < 4; ++i) gload_lds16(srcB[i], &lB[1][dAB[i]]);
#pragma unroll
  for (int i = 0; i < 4; ++i) gload_lds16(srcA[i], &lA[1][dAB[i]]);
#pragma unroll
  for (int i = 0; i < 4; ++i) { srcA[i] += BK; srcB[i] += BK; }
  VMCNT(8)  // tile0 retired
  __builtin_amdgcn_s_barrier();

  bf16x8 aF0[4][2], aF1[4][2], bN0[2][2], bN1[2][2];

  for (int t = 0; t < NKT; ++t) {
    const int p = t & 1;
    const unsigned short* Ab = &lA[p][0];
    const unsigned short* Bb = &lB[p][0];
    unsigned short* Aw = &lA[p][0];  // t+2 has same parity
    unsigned short* Bw = &lB[p][0];
    const bool stg = (t < NKT - 2);

    // ---------- ph0: read aF0 + bN0, MFMA Q(0,0) ----------
    RD_A(aF0, Ab, 0)
    RD_B(bN0, Bb, 0)
    __builtin_amdgcn_sched_barrier(0);
    __builtin_amdgcn_s_barrier();
    LGKM0
    __builtin_amdgcn_s_setprio(1);
    QUAD(0, 0, aF0, bN0)
    __builtin_amdgcn_s_setprio(0);
    __builtin_amdgcn_s_barrier();

    // ---------- ph1: read bN1, MFMA Q(0,1) ----------
    RD_B(bN1, Bb, 2)
    __builtin_amdgcn_sched_barrier(0);
    __builtin_amdgcn_s_barrier();
    LGKM0
    __builtin_amdgcn_s_setprio(1);
    QUAD(0, 1, aF0, bN1)
    __builtin_amdgcn_s_setprio(0);
    __builtin_amdgcn_s_barrier();

    // ---------- ph2: read aF1, stage B(t+2), MFMA Q(1,1) ----------
    // (all B reads of this tile completed at ph1's lgkm -> B buffer overwrite safe)
    RD_A(aF1, Ab, 4)
    if (stg) {
#pragma unroll
      for (int i = 0; i < 4; ++i) { gload_lds16(srcB[i], Bw + dAB[i]); srcB[i] += BK; }
    }
    __builtin_amdgcn_sched_barrier(0);
    __builtin_amdgcn_s_barrier();
    LGKM0
    __builtin_amdgcn_s_setprio(1);
    QUAD(1, 1, aF1, bN1)
    __builtin_amdgcn_s_setprio(0);
    __builtin_amdgcn_s_barrier();

    // ---------- ph3: stage A(t+2), MFMA Q(1,0), counted vmcnt ----------
    // (all A reads of this tile completed at ph2's lgkm -> A buffer overwrite safe)
    if (stg) {
#pragma unroll
      for (int i = 0; i < 4; ++i) { gload_lds16(srcA[i], Aw + dAB[i]); srcA[i] += BK; }
    }
    __builtin_amdgcn_sched_barrier(0);
    __builtin_amdgcn_s_barrier();
    __builtin_amdgcn_s_setprio(1);
    QUAD(1, 0, aF1, bN0)
    __builtin_amdgcn_s_setprio(0);
    if (t < NKT - 2) {
      VMCNT(8)  // retire tile t+1 fully; keep t+2's 8 loads in flight (never 0)
    } else if (t == NKT - 2) {
      VMCNT(0)  // drain last staged tile (issued 2 tiles ago; cheap)
    }
    __builtin_amdgcn_s_barrier();
  }

  // ---- epilogue: quad holds {f,i,s,p} of same output element (gate = lane&3) ----
  const int g  = lane & 3;
  const int qx = ll >> 2;
  const float aa = (g == 3) ? 2.0f : 1.0f;   // tanh(z) = 2*sigm(2z) - 1
  const float cc = (g == 3) ? -1.0f : 0.0f;
  const float* bptr = (g == 0) ? bias_f : (g == 1) ? bias_i : (g == 2) ? bias_s : bias_p;
  const bool b0 = (g & 1) != 0;
  const bool b1 = (g & 2) != 0;

#pragma unroll
  for (int n = 0; n < 4; ++n) {
    const int oc = bcol * 64 + wc * 16 + n * 4 + qx;
    const float bv = bptr[oc];
#pragma unroll
    for (int m = 0; m < 8; ++m) {
      const int rbase = brow * 256 + wr * 128 + m * 16 + lg * 4;
      float act[4], x1[4], x2[4], x3[4], hv[4];
#pragma unroll
      for (int j = 0; j < 4; ++j) {
        float z = acc[m][n][j] + bv;
        act[j] = aa * sigm(aa * z) + cc;
      }
#pragma unroll
      for (int j = 0; j < 4; ++j) {
        x1[j] = dppf<0xB1>(act[j]);  // quad_perm [1,0,3,2] : xor 1
        x2[j] = dppf<0x4E>(act[j]);  // quad_perm [2,3,0,1] : xor 2
        x3[j] = dppf<0x4E>(x1[j]);   // xor 3
      }
#pragma unroll
      for (int j = 0; j < 4; ++j) {
        // X[k] = activation of gate k: X[0]=act(own), X[1]=x1, X[2]=x2, X[3]=x3 (xor by g)
        float F  = b1 ? (b0 ? x3[j] : x2[j]) : (b0 ? x1[j] : act[j]);  // gate 0
        float S  = b1 ? (b0 ? x1[j] : act[j]) : (b0 ? x3[j] : x2[j]);  // gate 2
        float IP = b0 ? (act[j] * x2[j]) : (x1[j] * x3[j]);            // gate1 * gate3
        float cv = c_in[(size_t)(rbase + j) * 1024 + oc];
        float cn = cv * F + IP;
        hv[j] = tanh_fast(cn) * S;
      }
      float hst = b1 ? (b0 ? hv[3] : hv[2]) : (b0 ? hv[1] : hv[0]);
      out[(size_t)(rbase + g) * 1024 + oc] = hst;
    }
  }
}

extern "C" void kernel_launch(void* const* d_in, const int* in_sizes, int n_in,
                              void* d_out, int out_size, void* d_ws, size_t ws_size,
                              hipStream_t stream) {
  const float* x  = (const float*)d_in[0];
  const float* h  = (const float*)d_in[1];
  const float* c  = (const float*)d_in[2];
  const float* Wf = (const float*)d_in[3];
  const float* bf = (const float*)d_in[4];
  const float* Wi = (const float*)d_in[5];
  const float* bi = (const float*)d_in[6];
  const float* Ws = (const float*)d_in[7];
  const float* bs = (const float*)d_in[8];
  const float* Wp = (const float*)d_in[9];
  const float* bp = (const float*)d_in[10];
  float* out = (float*)d_out;

  unsigned short* ws = (unsigned short*)d_ws;
  unsigned short* hx  = ws;                        // 4096*2048 bf16 = 16 MB
  unsigned short* wt2 = ws + (size_t)4096 * 2048;  // 4096*2048 bf16 = 16 MB (gate-interleaved)

  pack_hx_kernel<<<(4096 * 2048 / 4) / 256, 256, 0, stream>>>(x, h, hx);

  dim3 tb(32, 8);
  dim3 tg(1024 / 32, 2048 / 32, 4);
  transpose_w4_kernel<<<tg, tb, 0, stream>>>(Wf, Wi, Ws, Wp, wt2);

  lstm_fused_kernel<<<256, 512, 0, stream>>>(hx, wt2, bf, bi, bs, bp, c, out);
}

// Round 6
// 87.828 us; speedup vs baseline: 1.2260x; 1.2260x over previous
//
#include <hip/hip_runtime.h>
#include <hip/hip_bf16.h>

typedef __attribute__((ext_vector_type(8))) short bf16x8;
typedef __attribute__((ext_vector_type(4))) float f32x4;

#define KDIM 2048
#define BK 64
#define NKT (KDIM / BK)

__device__ __forceinline__ unsigned short f2bf(float f) {
  union { float fv; unsigned int u; } c; c.fv = f;
  unsigned int u = c.u;
  unsigned int r = (u + 0x7FFFu + ((u >> 16) & 1u)) >> 16;
  return (unsigned short)r;
}

__device__ __forceinline__ void gload_lds16(const unsigned short* g, unsigned short* l) {
  auto gp = reinterpret_cast<const __attribute__((address_space(1))) unsigned int*>(
      reinterpret_cast<uintptr_t>(g));
  auto lp = reinterpret_cast<__attribute__((address_space(3))) unsigned int*>(
      reinterpret_cast<uintptr_t>(l));
  __builtin_amdgcn_global_load_lds(gp, lp, 16, 0, 0);
}

__device__ __forceinline__ float sigm(float z) { return 1.0f / (1.0f + __expf(-z)); }
__device__ __forceinline__ float tanh_fast(float z) { return 1.0f - 2.0f / (__expf(2.0f * z) + 1.0f); }

// Build hx = [x | h] as bf16 [4096][2048]
__global__ void pack_hx_kernel(const float* __restrict__ x, const float* __restrict__ h,
                               unsigned short* __restrict__ hx) {
  int idx = (blockIdx.x * blockDim.x + threadIdx.x) * 4;
  int row = idx >> 11;
  int col = idx & 2047;
  const float* src = (col < 1024) ? (x + (size_t)row * 1024 + col)
                                  : (h + (size_t)row * 1024 + (col - 1024));
  float4 v = *reinterpret_cast<const float4*>(src);
  ushort4 o = make_ushort4(f2bf(v.x), f2bf(v.y), f2bf(v.z), f2bf(v.w));
  *reinterpret_cast<ushort4*>(hx + idx) = o;
}

// All four W [2048][1024] f32 -> Wt [4][1024][2048] bf16 in one launch (z = gate)
__global__ void transpose_w4_kernel(const float* __restrict__ W0, const float* __restrict__ W1,
                                    const float* __restrict__ W2, const float* __restrict__ W3,
                                    unsigned short* __restrict__ Wt) {
  __shared__ float tile[32][33];
  const int g = blockIdx.z;
  const float* W = (g == 0) ? W0 : (g == 1) ? W1 : (g == 2) ? W2 : W3;
  unsigned short* T = Wt + (size_t)g * 1024 * 2048;
  int n0 = blockIdx.x * 32;
  int k0 = blockIdx.y * 32;
  int tx = threadIdx.x;
  int ty = threadIdx.y;
#pragma unroll
  for (int i = 0; i < 4; ++i)
    tile[ty + 8 * i][tx] = W[(size_t)(k0 + ty + 8 * i) * 1024 + (n0 + tx)];
  __syncthreads();
#pragma unroll
  for (int i = 0; i < 4; ++i)
    T[(size_t)(n0 + ty + 8 * i) * 2048 + (k0 + tx)] = f2bf(tile[tx][ty + 8 * i]);
}

// ---- inline-asm LDS read (invisible to compiler's waitcnt insertion) ----
#define DSR(dst, base, imm) \
  asm volatile("ds_read_b128 %0, %1 offset:%c2" : "=v"(dst) : "v"(base), "i"(imm))

#define LGKM(N)                                                   \
  do {                                                            \
    asm volatile("s_waitcnt lgkmcnt(" #N ")" ::: "memory");       \
    __builtin_amdgcn_sched_barrier(0);                            \
  } while (0)

#define VMC(N)                                                    \
  do {                                                            \
    asm volatile("s_waitcnt vmcnt(" #N ")" ::: "memory");         \
    __builtin_amdgcn_sched_barrier(0);                            \
  } while (0)

#define GMF(G, S)                                                                   \
  __builtin_amdgcn_s_setprio(1);                                                    \
  _Pragma("unroll") for (int m = 0; m < 4; ++m)                                     \
      _Pragma("unroll") for (int n = 0; n < 2; ++n) {                               \
    acc[G][m][n] = __builtin_amdgcn_mfma_f32_16x16x32_bf16(aF[m][0], S[n][0],       \
                                                           acc[G][m][n], 0, 0, 0); \
    acc[G][m][n] = __builtin_amdgcn_mfma_f32_16x16x32_bf16(aF[m][1], S[n][1],       \
                                                           acc[G][m][n], 0, 0, 0); \
  }                                                                                 \
  __builtin_amdgcn_s_setprio(0);

#define STAGE(P)                                                        \
  {                                                                     \
    _Pragma("unroll") for (int i = 0; i < 4; ++i)                       \
        gload_lds16(srcA[i], &lA[P][dA[i]]);                            \
    _Pragma("unroll") for (int g = 0; g < 4; ++g)                       \
        gload_lds16(srcB[g], &lB[P][dB[g]]);                            \
    _Pragma("unroll") for (int i = 0; i < 4; ++i) srcA[i] += BK;        \
    _Pragma("unroll") for (int g = 0; g < 4; ++g) srcB[g] += BK;        \
  }

// Per K-tile: issue reads -> counted lgkm -> MFMA groups (per-wave pipeline),
// then 1 barrier, stage t+2, counted vmcnt (never 0 mid-loop), 1 barrier.
#define TILE(P, T)                                                      \
  {                                                                     \
    bf16x8 aF[4][2], S0[2][2], S1[2][2], S2[2][2];                      \
    _Pragma("unroll") for (int m = 0; m < 4; ++m) {                     \
      DSR(aF[m][0], a_base0, (P)*32768 + m * 2048);                     \
      DSR(aF[m][1], a_base1, (P)*32768 + m * 2048);                     \
    }                                                                   \
    _Pragma("unroll") for (int n = 0; n < 2; ++n) {                     \
      DSR(S0[n][0], b_base0, (P)*32768 + 0 * 8192 + n * 2048);          \
      DSR(S0[n][1], b_base1, (P)*32768 + 0 * 8192 + n * 2048);          \
    }                                                                   \
    _Pragma("unroll") for (int n = 0; n < 2; ++n) {                     \
      DSR(S1[n][0], b_base0, (P)*32768 + 1 * 8192 + n * 2048);          \
      DSR(S1[n][1], b_base1, (P)*32768 + 1 * 8192 + n * 2048);          \
    }                                                                   \
    LGKM(4); /* aF + S0 complete */                                     \
    GMF(0, S0)                                                          \
    _Pragma("unroll") for (int n = 0; n < 2; ++n) {                     \
      DSR(S2[n][0], b_base0, (P)*32768 + 2 * 8192 + n * 2048);          \
      DSR(S2[n][1], b_base1, (P)*32768 + 2 * 8192 + n * 2048);          \
    }                                                                   \
    LGKM(4); /* S1 complete */                                          \
    GMF(1, S1)                                                          \
    _Pragma("unroll") for (int n = 0; n < 2; ++n) {                     \
      DSR(S0[n][0], b_base0, (P)*32768 + 3 * 8192 + n * 2048);          \
      DSR(S0[n][1], b_base1, (P)*32768 + 3 * 8192 + n * 2048);          \
    }                                                                   \
    LGKM(4); /* S2 complete */                                          \
    GMF(2, S2)                                                          \
    LGKM(0); /* S0' (gate3) complete */                                 \
    GMF(3, S0)                                                          \
    __builtin_amdgcn_s_barrier();                                       \
    __builtin_amdgcn_sched_barrier(0);                                  \
    if ((T) < NKT - 2) STAGE(P)                                         \
    if ((T) < NKT - 2) { VMC(8); } else { VMC(0); }                     \
    __builtin_amdgcn_s_barrier();                                       \
    __builtin_amdgcn_sched_barrier(0);                                  \
  }

// Fused 4-gate GEMM + LSTM epilogue.
// Grid: 256 blocks, 512 threads (8 waves, 4M x 2N; wave tile 64 rows x 32 cols x 4 gates).
__global__ __launch_bounds__(512, 2) void lstm_fused_kernel(
    const unsigned short* __restrict__ hx,
    const unsigned short* __restrict__ wtb,
    const float* __restrict__ bias_f,
    const float* __restrict__ bias_i,
    const float* __restrict__ bias_s,
    const float* __restrict__ bias_p,
    const float* __restrict__ c_in,
    float* __restrict__ out) {
  __shared__ unsigned short lA[2][256 * BK];      // 2 x 32 KB
  __shared__ unsigned short lB[2][4 * 64 * BK];   // 2 x 32 KB

  const int tid  = threadIdx.x;
  const int lane = tid & 63;
  const int wid  = tid >> 6;
  const int wr   = wid >> 1;  // 0..3 : 64-row slice
  const int wc   = wid & 1;   // 0..1 : 32-col slice
  const int lg   = lane >> 4;
  const int ll   = lane & 15;

  // bijective XCD swizzle (256 % 8 == 0)
  const int wg   = (blockIdx.x & 7) * 32 + (blockIdx.x >> 3);
  const int brow = wg >> 4;  // 0..15
  const int bcol = wg & 15;  // 0..15

  // ---- staging descriptors ----
  const unsigned short* srcA[4];
  unsigned int dA[4];
#pragma unroll
  for (int i = 0; i < 4; ++i) {
    int s = i * 512 + tid;
    int r = s >> 3, sch = s & 7;
    int ch = sch ^ (r & 7);
    srcA[i] = hx + (size_t)(brow * 256 + r) * KDIM + ch * 8;
    dA[i] = s * 8;
  }
  const unsigned short* srcB[4];
  unsigned int dB[4];
  {
    int r = tid >> 3, sch = tid & 7;
    int ch = sch ^ (r & 7);
#pragma unroll
    for (int g = 0; g < 4; ++g) {
      srcB[g] = wtb + (size_t)g * 1024 * 2048 + (size_t)(bcol * 64 + r) * KDIM + ch * 8;
      dB[g] = g * 4096 + tid * 8;
    }
  }

  // ---- per-lane LDS byte addresses for fragment reads ----
  const unsigned ldsA = (unsigned)(uintptr_t)(&lA[0][0]);
  const unsigned ldsB = (unsigned)(uintptr_t)(&lB[0][0]);
  const int ch0 = lg ^ (ll & 7);
  const int ch1 = ch0 ^ 4;
  const unsigned a_base0 = ldsA + (unsigned)(((wr * 64 + ll) * 64 + ch0 * 8) * 2);
  const unsigned a_base1 = ldsA + (unsigned)(((wr * 64 + ll) * 64 + ch1 * 8) * 2);
  const unsigned b_base0 = ldsB + (unsigned)(((wc * 32 + ll) * 64 + ch0 * 8) * 2);
  const unsigned b_base1 = ldsB + (unsigned)(((wc * 32 + ll) * 64 + ch1 * 8) * 2);

  f32x4 acc[4][4][2];
#pragma unroll
  for (int g = 0; g < 4; ++g)
#pragma unroll
    for (int m = 0; m < 4; ++m)
#pragma unroll
      for (int n = 0; n < 2; ++n)
        acc[g][m][n] = (f32x4)(0.0f);

  // ---- prologue: stage tiles 0 (buf0) and 1 (buf1) ----
  STAGE(0)
  STAGE(1)
  VMC(8);  // tile0 retired (first 8 of 16)
  __builtin_amdgcn_s_barrier();
  __builtin_amdgcn_sched_barrier(0);

  for (int t = 0; t < NKT; t += 2) {
    TILE(0, t)
    TILE(1, t + 1)
  }

  // ---- epilogue: gates + cell update, store h_new (coalesced) ----
  const int row0 = brow * 256 + wr * 64;
  const int col0 = bcol * 64 + wc * 32;
  float bv[4][2];
#pragma unroll
  for (int n = 0; n < 2; ++n) {
    int col = col0 + n * 16 + ll;
    bv[0][n] = bias_f[col];
    bv[1][n] = bias_i[col];
    bv[2][n] = bias_s[col];
    bv[3][n] = bias_p[col];
  }
#pragma unroll
  for (int m = 0; m < 4; ++m)
#pragma unroll
    for (int n = 0; n < 2; ++n)
#pragma unroll
      for (int j = 0; j < 4; ++j) {
        int row = row0 + m * 16 + lg * 4 + j;
        int col = col0 + n * 16 + ll;
        float zf = acc[0][m][n][j] + bv[0][n];
        float zi = acc[1][m][n][j] + bv[1][n];
        float zs = acc[2][m][n][j] + bv[2][n];
        float zp = acc[3][m][n][j] + bv[3][n];
        float fg = sigm(zf);
        float ig = sigm(zi);
        float sg = sigm(zs);
        float pg = tanh_fast(zp);
        float cn = c_in[(size_t)row * 1024 + col] * fg + ig * pg;
        out[(size_t)row * 1024 + col] = tanh_fast(cn) * sg;
      }
}

extern "C" void kernel_launch(void* const* d_in, const int* in_sizes, int n_in,
                              void* d_out, int out_size, void* d_ws, size_t ws_size,
                              hipStream_t stream) {
  const float* x  = (const float*)d_in[0];
  const float* h  = (const float*)d_in[1];
  const float* c  = (const float*)d_in[2];
  const float* Wf = (const float*)d_in[3];
  const float* bf = (const float*)d_in[4];
  const float* Wi = (const float*)d_in[5];
  const float* bi = (const float*)d_in[6];
  const float* Ws = (const float*)d_in[7];
  const float* bs = (const float*)d_in[8];
  const float* Wp = (const float*)d_in[9];
  const float* bp = (const float*)d_in[10];
  float* out = (float*)d_out;

  unsigned short* ws = (unsigned short*)d_ws;
  unsigned short* hx  = ws;                        // 4096*2048 bf16 = 16 MB
  unsigned short* wtb = ws + (size_t)4096 * 2048;  // 4*1024*2048 bf16 = 16 MB

  pack_hx_kernel<<<(4096 * 2048 / 4) / 256, 256, 0, stream>>>(x, h, hx);

  dim3 tb(32, 8);
  dim3 tg(1024 / 32, 2048 / 32, 4);
  transpose_w4_kernel<<<tg, tb, 0, stream>>>(Wf, Wi, Ws, Wp, wtb);

  lstm_fused_kernel<<<256, 512, 0, stream>>>(hx, wtb, bf, bi, bs, bp, c, out);
}